// Round 1
// baseline (225.778 us; speedup 1.0000x reference)
//
#include <hip/hip_runtime.h>
#include <stdint.h>

// DiagonalSSM: out = (scan_t tanh(exp(-A)*state + (x@Bw^T)_t)) @ Wo^T + bo
// Shapes fixed per reference: B=8, S=2048, Din=Dstate=Dout=1024. fp32 in/out.
// Plan: cvt x,Bw,Wo -> bf16 (ws); GEMM1 (MFMA bf16, f32 acc) -> Bx f32 in d_out;
//       scan (f32, latency-optimized, deep prefetch) -> h bf16 in ws;
//       GEMM2 (+bias) -> d_out f32.

typedef __attribute__((ext_vector_type(8))) short bf16x8;
typedef __attribute__((ext_vector_type(4))) float f32x4;
typedef __attribute__((ext_vector_type(8))) unsigned short u16x8;

static __device__ __forceinline__ unsigned short f2b(float f) {
  unsigned u = __builtin_bit_cast(unsigned, f);
  unsigned r = 0x7FFFu + ((u >> 16) & 1u);  // round-to-nearest-even
  return (unsigned short)((u + r) >> 16);
}

// global -> LDS async copy, 16B per lane; LDS dest = wave-uniform base + lane*16.
static __device__ __forceinline__ void gload_lds16(const void* g, void* l) {
  __builtin_amdgcn_global_load_lds(
      (const __attribute__((address_space(1))) void*)(uintptr_t)g,
      (__attribute__((address_space(3))) void*)(unsigned)(uintptr_t)l,
      16, 0, 0);
}

// ---------------- f32 -> bf16 convert, 8 elems/thread ----------------
__global__ __launch_bounds__(256) void cvt_f32_bf16(const float* __restrict__ in,
                                                    unsigned short* __restrict__ out,
                                                    int n8) {
  int i = blockIdx.x * 256 + threadIdx.x;
  if (i >= n8) return;
  const float4* p = (const float4*)in;
  float4 v0 = p[2 * (size_t)i];
  float4 v1 = p[2 * (size_t)i + 1];
  u16x8 o;
  o[0] = f2b(v0.x); o[1] = f2b(v0.y); o[2] = f2b(v0.z); o[3] = f2b(v0.w);
  o[4] = f2b(v1.x); o[5] = f2b(v1.y); o[6] = f2b(v1.z); o[7] = f2b(v1.w);
  *(u16x8*)(out + 8 * (size_t)i) = o;
}

// ------- C[M][N] = A[M][K] @ B[N][K]^T (+bias); bf16 in, f32 out -------
// 128x128 tile, BK=32, 4 waves in 2x2, each wave 64x64 = 4x4 mfma_16x16x32 frags.
template <int ADD_BIAS>
__global__ __launch_bounds__(256) void gemm_nt(const unsigned short* __restrict__ A,
                                               const unsigned short* __restrict__ B,
                                               float* __restrict__ C,
                                               const float* __restrict__ bias,
                                               int M, int N, int K) {
  constexpr int BM = 128, BN = 128, BK = 32;
  __shared__ unsigned short As[BM * BK];  // 8 KiB, row-major [128][32]
  __shared__ unsigned short Bs[BN * BK];  // 8 KiB
  const int tid = threadIdx.x;
  const int wave = tid >> 6;
  const int lane = tid & 63;
  const int wr = wave >> 1, wc = wave & 1;
  const int m0 = blockIdx.y * BM, n0 = blockIdx.x * BN;

  // staging: chunk = 1KiB = 16 rows; lane covers row chunk*16 + lane/4, col (lane&3)*8
  const int srow = lane >> 2;
  const int scol = (lane & 3) * 8;

  const int l16 = lane & 15;
  const int kof = (lane >> 4) * 8;  // k-offset of this lane's 8 contiguous bf16

  f32x4 acc[4][4] = {};

  for (int k0 = 0; k0 < K; k0 += BK) {
#pragma unroll
    for (int i = 0; i < 2; ++i) {
      const int chunk = wave * 2 + i;  // 0..7
      const int row = chunk * 16 + srow;
      gload_lds16(A + (size_t)(m0 + row) * K + (k0 + scol), (char*)As + chunk * 1024);
      gload_lds16(B + (size_t)(n0 + row) * K + (k0 + scol), (char*)Bs + chunk * 1024);
    }
    __syncthreads();  // drains vmcnt -> staged data visible

    bf16x8 af[4], bfr[4];
#pragma unroll
    for (int i = 0; i < 4; ++i) {
      af[i]  = *(const bf16x8*)(As + (wr * 64 + i * 16 + l16) * BK + kof);
      bfr[i] = *(const bf16x8*)(Bs + (wc * 64 + i * 16 + l16) * BK + kof);
    }
#pragma unroll
    for (int i = 0; i < 4; ++i)
#pragma unroll
      for (int j = 0; j < 4; ++j)
        acc[i][j] = __builtin_amdgcn_mfma_f32_16x16x32_bf16(af[i], bfr[j], acc[i][j], 0, 0, 0);
    __syncthreads();
  }

  // C/D layout (m89-verified): col = lane&15, row = (lane>>4)*4 + reg
  const int cr = (lane >> 4) * 4;
  const int cc = lane & 15;
#pragma unroll
  for (int j = 0; j < 4; ++j) {
    const int gc = n0 + wc * 64 + j * 16 + cc;
    const float bv = ADD_BIAS ? bias[gc] : 0.0f;
#pragma unroll
    for (int i = 0; i < 4; ++i) {
      const size_t base = (size_t)(m0 + wr * 64 + i * 16 + cr) * N + gc;
#pragma unroll
      for (int r = 0; r < 4; ++r) C[base + (size_t)r * N] = acc[i][j][r] + bv;
    }
  }
}

// ---------------- sequential tanh scan over t ----------------
// One thread per (b, n) channel: 8192 threads, 128 one-wave blocks (~128 CUs).
// tanh(u) = 1 - 2/(exp2(C2*u)+1), C2 = 2*log2(e). Deep 2x16 prefetch hides
// HBM/L3 latency under the ~450-cycle dependent chain of each 16-step chunk.
__global__ __launch_bounds__(64) void scan_kernel(const float* __restrict__ Bx,
                                                  const float* __restrict__ Av,
                                                  unsigned short* __restrict__ h) {
  constexpr int S = 2048, D = 1024, U = 16;
  const int gid = blockIdx.x * 64 + threadIdx.x;
  const int b = gid >> 10;
  const int n = gid & (D - 1);
  constexpr float LOG2E = 1.44269504088896340736f;
  constexpr float C2 = 2.0f * LOG2E;

  const float a = fminf(Av[n], 10.0f);
  const float dec = __builtin_amdgcn_exp2f(-a * LOG2E);  // exp(-min(A,10))
  const float dkC = dec * C2;

  const float* bp = Bx + (size_t)b * S * D + n;
  unsigned short* hp = h + (size_t)b * S * D + n;

  float buf0[U], buf1[U];
#pragma unroll
  for (int j = 0; j < U; ++j) buf0[j] = bp[(size_t)j * D];
#pragma unroll
  for (int j = 0; j < U; ++j) buf1[j] = bp[(size_t)(U + j) * D];

  float state = 0.0f;
  for (int t0 = 0; t0 < S; t0 += 2 * U) {
    float c0[U];
#pragma unroll
    for (int j = 0; j < U; ++j) c0[j] = buf0[j] * C2;  // off critical chain
    if (t0 + 2 * U < S) {
#pragma unroll
      for (int j = 0; j < U; ++j) buf0[j] = bp[(size_t)(t0 + 2 * U + j) * D];
    }
#pragma unroll
    for (int j = 0; j < U; ++j) {
      float w = fmaf(dkC, state, c0[j]);
      float e = __builtin_amdgcn_exp2f(w);
      float r = __builtin_amdgcn_rcpf(e + 1.0f);
      state = fmaf(-2.0f, r, 1.0f);
      hp[(size_t)(t0 + j) * D] = f2b(state);
    }
    float c1[U];
#pragma unroll
    for (int j = 0; j < U; ++j) c1[j] = buf1[j] * C2;
    if (t0 + 3 * U < S) {
#pragma unroll
      for (int j = 0; j < U; ++j) buf1[j] = bp[(size_t)(t0 + 3 * U + j) * D];
    }
#pragma unroll
    for (int j = 0; j < U; ++j) {
      float w = fmaf(dkC, state, c1[j]);
      float e = __builtin_amdgcn_exp2f(w);
      float r = __builtin_amdgcn_rcpf(e + 1.0f);
      state = fmaf(-2.0f, r, 1.0f);
      hp[(size_t)(t0 + U + j) * D] = f2b(state);
    }
  }
}

extern "C" void kernel_launch(void* const* d_in, const int* in_sizes, int n_in,
                              void* d_out, int out_size, void* d_ws, size_t ws_size,
                              hipStream_t stream) {
  const float* x  = (const float*)d_in[0];
  const float* Av = (const float*)d_in[1];
  const float* Bw = (const float*)d_in[2];
  const float* Wo = (const float*)d_in[3];
  const float* bo = (const float*)d_in[4];
  float* out = (float*)d_out;

  const int Bsz = 8, S = 2048, Din = 1024, Dst = 1024, Dout = 1024;
  const int M = Bsz * S;  // 16384

  // ws layout (bytes): x_bf16 [0,32M), h_bf16 [32M,64M), Bw_bf16, Wo_bf16 (~68MB total)
  char* ws = (char*)d_ws;
  unsigned short* x_bf  = (unsigned short*)ws;
  unsigned short* h_bf  = (unsigned short*)(ws + (size_t)M * Din * 2);
  unsigned short* Bw_bf = (unsigned short*)(ws + (size_t)M * Din * 4);
  unsigned short* Wo_bf = (unsigned short*)(ws + (size_t)M * Din * 4 + (size_t)Dst * Din * 2);

  float* Bx = out;  // d_out (f32, exactly M*Dst) doubles as pre-scan scratch

  {
    int n8 = M * Din / 8;
    cvt_f32_bf16<<<(n8 + 255) / 256, 256, 0, stream>>>(x, x_bf, n8);
  }
  {
    int n8 = Dst * Din / 8;
    cvt_f32_bf16<<<(n8 + 255) / 256, 256, 0, stream>>>(Bw, Bw_bf, n8);
  }
  {
    int n8 = Dout * Dst / 8;
    cvt_f32_bf16<<<(n8 + 255) / 256, 256, 0, stream>>>(Wo, Wo_bf, n8);
  }

  gemm_nt<0><<<dim3(Dst / 128, M / 128), 256, 0, stream>>>(x_bf, Bw_bf, Bx, nullptr, M, Dst, Din);
  scan_kernel<<<dim3((Bsz * Dst) / 64), 64, 0, stream>>>(Bx, Av, h_bf);
  gemm_nt<1><<<dim3(Dout / 128, M / 128), 256, 0, stream>>>(h_bf, Wo_bf, out, bo, M, Dout, Dst);
}

// Round 2
// 221.395 us; speedup vs baseline: 1.0198x; 1.0198x over previous
//
#include <hip/hip_runtime.h>
#include <stdint.h>

// DiagonalSSM: out = (scan_t tanh(exp(-A)*state + (x@Bw^T)_t)) @ Wo^T + bo
// B=8, S=2048, Din=Dstate=Dout=1024, fp32 in/out.
//
// Pipeline:
//   cvt x,Bw -> bf16; cvt Wo -> bf16 * (-2); dkc[n] = C2*exp(-min(A,10));
//   bias2[o] = bo[o] + rowsum(Wo)[o]
//   GEMM1 (MFMA bf16): c''[m][n] = C2*(x@Bw^T) + dkc[n]   -> f32 in d_out
//   scan (r-space, 4-dep chain): r_t = rcp(exp2(fma(-2*C2*dec, r_{t-1}, c''_t))+1)
//        store bf16(r) -> ws                                (s = 1-2r)
//   GEMM2: out = r @ (-2*Wo)^T + bias2                      -> f32 d_out

typedef __attribute__((ext_vector_type(8))) short bf16x8;
typedef __attribute__((ext_vector_type(4))) float f32x4;
typedef __attribute__((ext_vector_type(8))) unsigned short u16x8;

#define C2F 2.88539008177792681472f  // 2*log2(e)
#define LOG2E 1.44269504088896340736f

static __device__ __forceinline__ unsigned short f2b(float f) {
  unsigned u = __builtin_bit_cast(unsigned, f);
  unsigned r = 0x7FFFu + ((u >> 16) & 1u);  // round-to-nearest-even
  return (unsigned short)((u + r) >> 16);
}

// global -> LDS async copy, 16B per lane; LDS dest = wave-uniform base + lane*16.
static __device__ __forceinline__ void gload_lds16(const void* g, void* l) {
  __builtin_amdgcn_global_load_lds(
      (const __attribute__((address_space(1))) void*)(uintptr_t)g,
      (__attribute__((address_space(3))) void*)(unsigned)(uintptr_t)l,
      16, 0, 0);
}

// ---------------- f32 -> bf16 convert (with scale), 8 elems/thread ----------------
__global__ __launch_bounds__(256) void cvt_f32_bf16(const float* __restrict__ in,
                                                    unsigned short* __restrict__ out,
                                                    float scale, int n8) {
  int i = blockIdx.x * 256 + threadIdx.x;
  if (i >= n8) return;
  const float4* p = (const float4*)in;
  float4 v0 = p[2 * (size_t)i];
  float4 v1 = p[2 * (size_t)i + 1];
  u16x8 o;
  o[0] = f2b(v0.x * scale); o[1] = f2b(v0.y * scale);
  o[2] = f2b(v0.z * scale); o[3] = f2b(v0.w * scale);
  o[4] = f2b(v1.x * scale); o[5] = f2b(v1.y * scale);
  o[6] = f2b(v1.z * scale); o[7] = f2b(v1.w * scale);
  *(u16x8*)(out + 8 * (size_t)i) = o;
}

// ---------------- dkc[n] = C2 * exp(-min(A[n],10)) ----------------
__global__ __launch_bounds__(256) void dkc_kernel(const float* __restrict__ Av,
                                                  float* __restrict__ dkc, int n) {
  int i = blockIdx.x * 256 + threadIdx.x;
  if (i >= n) return;
  float a = fminf(Av[i], 10.0f);
  dkc[i] = C2F * __builtin_amdgcn_exp2f(-a * LOG2E);
}

// ---------------- bias2[o] = bo[o] + sum_n Wo[o][n]  (one wave per row) ----------------
__global__ __launch_bounds__(256) void bias2_kernel(const float* __restrict__ Wo,
                                                    const float* __restrict__ bo,
                                                    float* __restrict__ bias2) {
  const int o = blockIdx.x * 4 + (threadIdx.x >> 6);
  const int lane = threadIdx.x & 63;
  const float4* row = (const float4*)(Wo + (size_t)o * 1024);
  float s = 0.0f;
#pragma unroll
  for (int k = 0; k < 4; ++k) {
    float4 v = row[lane + k * 64];
    s += v.x + v.y + v.z + v.w;
  }
#pragma unroll
  for (int off = 32; off; off >>= 1) s += __shfl_down(s, off);
  if (lane == 0) bias2[o] = s + bo[o];
}

// ------- C[M][N] = A[M][K] @ B[N][K]^T epilogue-fused; bf16 in, f32 out -------
// 128x128 tile, BK=32, 4 waves in 2x2, each wave 64x64 = 4x4 mfma_16x16x32 frags.
// MODE 0: C = acc*C2 + bv[col]   (GEMM1: c'' = C2*Bx + dkc)
// MODE 1: C = acc + bv[col]      (GEMM2: out = r@Wo'^T + bias2)
template <int MODE>
__global__ __launch_bounds__(256) void gemm_nt(const unsigned short* __restrict__ A,
                                               const unsigned short* __restrict__ B,
                                               float* __restrict__ C,
                                               const float* __restrict__ bv,
                                               int M, int N, int K) {
  constexpr int BM = 128, BN = 128, BK = 32;
  __shared__ unsigned short As[BM * BK];  // 8 KiB, row-major [128][32]
  __shared__ unsigned short Bs[BN * BK];  // 8 KiB
  const int tid = threadIdx.x;
  const int wave = tid >> 6;
  const int lane = tid & 63;
  const int wr = wave >> 1, wc = wave & 1;
  const int m0 = blockIdx.y * BM, n0 = blockIdx.x * BN;

  const int srow = lane >> 2;
  const int scol = (lane & 3) * 8;

  const int l16 = lane & 15;
  const int kof = (lane >> 4) * 8;

  f32x4 acc[4][4] = {};

  for (int k0 = 0; k0 < K; k0 += BK) {
#pragma unroll
    for (int i = 0; i < 2; ++i) {
      const int chunk = wave * 2 + i;  // 0..7
      const int row = chunk * 16 + srow;
      gload_lds16(A + (size_t)(m0 + row) * K + (k0 + scol), (char*)As + chunk * 1024);
      gload_lds16(B + (size_t)(n0 + row) * K + (k0 + scol), (char*)Bs + chunk * 1024);
    }
    __syncthreads();

    bf16x8 af[4], bfr[4];
#pragma unroll
    for (int i = 0; i < 4; ++i) {
      af[i]  = *(const bf16x8*)(As + (wr * 64 + i * 16 + l16) * BK + kof);
      bfr[i] = *(const bf16x8*)(Bs + (wc * 64 + i * 16 + l16) * BK + kof);
    }
#pragma unroll
    for (int i = 0; i < 4; ++i)
#pragma unroll
      for (int j = 0; j < 4; ++j)
        acc[i][j] = __builtin_amdgcn_mfma_f32_16x16x32_bf16(af[i], bfr[j], acc[i][j], 0, 0, 0);
    __syncthreads();
  }

  // C/D layout (m89-verified): col = lane&15, row = (lane>>4)*4 + reg
  const int cr = (lane >> 4) * 4;
  const int cc = lane & 15;
#pragma unroll
  for (int j = 0; j < 4; ++j) {
    const int gc = n0 + wc * 64 + j * 16 + cc;
    const float b = bv[gc];
#pragma unroll
    for (int i = 0; i < 4; ++i) {
      const size_t base = (size_t)(m0 + wr * 64 + i * 16 + cr) * N + gc;
#pragma unroll
      for (int r = 0; r < 4; ++r) {
        float v = MODE == 0 ? fmaf(acc[i][j][r], C2F, b) : (acc[i][j][r] + b);
        C[base + (size_t)r * N] = v;
      }
    }
  }
}

// ---------------- sequential scan over t, r-space ----------------
// One thread per (b,n): 8192 threads. Chain per step (4 dependent ops):
//   w2 = fma(m2dk, r, c''_t); e = exp2(w2); r = rcp(e+1)
// c'' comes pre-scaled (+dkc) from GEMM1's epilogue. Store bf16(r).
// 4x8 rotating prefetch buffers, ~24-step (~700cy) prefetch distance.
__global__ __launch_bounds__(64) void scan_kernel(const float* __restrict__ Bx,
                                                  const float* __restrict__ Av,
                                                  unsigned short* __restrict__ h) {
  constexpr int S = 2048, D = 1024, U = 8;
  const unsigned gid = blockIdx.x * 64 + threadIdx.x;
  const unsigned b = gid >> 10;
  const unsigned n = gid & (D - 1);

  const float a = fminf(Av[n], 10.0f);
  const float dec = __builtin_amdgcn_exp2f(-a * LOG2E);
  const float m2dk = -2.0f * C2F * dec;

  const unsigned base = b * (unsigned)(S * D) + n;  // 32-bit offsets -> saddr+voffset

  float b0[U], b1[U], b2[U], b3[U];
#pragma unroll
  for (int j = 0; j < U; ++j) b0[j] = Bx[base + (0 * U + j) * D];
#pragma unroll
  for (int j = 0; j < U; ++j) b1[j] = Bx[base + (1 * U + j) * D];
#pragma unroll
  for (int j = 0; j < U; ++j) b2[j] = Bx[base + (2 * U + j) * D];
#pragma unroll
  for (int j = 0; j < U; ++j) b3[j] = Bx[base + (3 * U + j) * D];

  float r = 0.5f;  // s = 1 - 2r = 0

#define STEP(BUF, T)                                              \
  {                                                               \
    float w = fmaf(m2dk, r, BUF);                                 \
    float e = __builtin_amdgcn_exp2f(w);                          \
    r = __builtin_amdgcn_rcpf(e + 1.0f);                          \
    unsigned u = __builtin_bit_cast(unsigned, r);                 \
    u = u + 0x7FFFu + ((u >> 16) & 1u);                           \
    h[base + (unsigned)(T) * D] = (unsigned short)(u >> 16);      \
  }

  for (int t0 = 0; t0 < S; t0 += 4 * U) {
#pragma unroll
    for (int j = 0; j < U; ++j) STEP(b0[j], t0 + j);
    if (t0 + 4 * U < S) {
#pragma unroll
      for (int j = 0; j < U; ++j) b0[j] = Bx[base + (t0 + 4 * U + j) * D];
    }
#pragma unroll
    for (int j = 0; j < U; ++j) STEP(b1[j], t0 + U + j);
    if (t0 + 5 * U < S) {
#pragma unroll
      for (int j = 0; j < U; ++j) b1[j] = Bx[base + (t0 + 5 * U + j) * D];
    }
#pragma unroll
    for (int j = 0; j < U; ++j) STEP(b2[j], t0 + 2 * U + j);
    if (t0 + 6 * U < S) {
#pragma unroll
      for (int j = 0; j < U; ++j) b2[j] = Bx[base + (t0 + 6 * U + j) * D];
    }
#pragma unroll
    for (int j = 0; j < U; ++j) STEP(b3[j], t0 + 3 * U + j);
    if (t0 + 7 * U < S) {
#pragma unroll
      for (int j = 0; j < U; ++j) b3[j] = Bx[base + (t0 + 7 * U + j) * D];
    }
  }
#undef STEP
}

extern "C" void kernel_launch(void* const* d_in, const int* in_sizes, int n_in,
                              void* d_out, int out_size, void* d_ws, size_t ws_size,
                              hipStream_t stream) {
  const float* x  = (const float*)d_in[0];
  const float* Av = (const float*)d_in[1];
  const float* Bw = (const float*)d_in[2];
  const float* Wo = (const float*)d_in[3];
  const float* bo = (const float*)d_in[4];
  float* out = (float*)d_out;

  const int Bsz = 8, S = 2048, Din = 1024, Dst = 1024, Dout = 1024;
  const int M = Bsz * S;  // 16384

  // ws layout: x_bf 32MB | r_bf 32MB | Bw_bf 2MB | Wo_bf 2MB | dkc 4KB | bias2 4KB
  char* ws = (char*)d_ws;
  unsigned short* x_bf  = (unsigned short*)ws;
  unsigned short* r_bf  = (unsigned short*)(ws + (size_t)M * Din * 2);
  unsigned short* Bw_bf = (unsigned short*)(ws + (size_t)M * Din * 4);
  unsigned short* Wo_bf = (unsigned short*)(ws + (size_t)M * Din * 4 + (size_t)Dst * Din * 2);
  float* dkc   = (float*)(ws + (size_t)M * Din * 4 + (size_t)Dst * Din * 4);
  float* bias2 = dkc + Dst;

  float* Bx = out;  // d_out doubles as pre-scan scratch (c'' values)

  { int n8 = M * Din / 8;
    cvt_f32_bf16<<<(n8 + 255) / 256, 256, 0, stream>>>(x, x_bf, 1.0f, n8); }
  { int n8 = Dst * Din / 8;
    cvt_f32_bf16<<<(n8 + 255) / 256, 256, 0, stream>>>(Bw, Bw_bf, 1.0f, n8); }
  { int n8 = Dout * Dst / 8;
    cvt_f32_bf16<<<(n8 + 255) / 256, 256, 0, stream>>>(Wo, Wo_bf, -2.0f, n8); }
  dkc_kernel<<<4, 256, 0, stream>>>(Av, dkc, Dst);
  bias2_kernel<<<Dout / 4, 256, 0, stream>>>(Wo, bo, bias2);

  gemm_nt<0><<<dim3(Dst / 128, M / 128), 256, 0, stream>>>(x_bf, Bw_bf, Bx, dkc, M, Dst, Din);
  scan_kernel<<<dim3((Bsz * Dst) / 64), 64, 0, stream>>>(Bx, Av, r_bf);
  gemm_nt<1><<<dim3(Dout / 128, M / 128), 256, 0, stream>>>(r_bf, Wo_bf, out, bias2, M, Dout, Dst);
}

// Round 3
// 177.223 us; speedup vs baseline: 1.2740x; 1.2492x over previous
//
#include <hip/hip_runtime.h>
#include <stdint.h>

// DiagonalSSM: out = (scan_t tanh(exp(-A)*state + (x@Bw^T)_t)) @ Wo^T + bo
// B=8, S=2048, Din=Dstate=Dout=1024, fp32 in/out.
//
// Pipeline:
//   cvt x,Bw -> bf16; cvt Wo -> bf16 * (-2); dkc[n] = C2*exp(-min(A,10));
//   bias2[o] = bo[o] + rowsum(Wo)[o]
//   GEMM1 (256^2 tile, 4-deep vmcnt-counted pipe): c'' = C2*(x@Bw^T)+dkc -> d_out
//   scan (r-space): r_t = rcp(exp2(fma(-2*C2*dec, r_{t-1}, c''_t))+1) -> bf16 ws
//   GEMM2: out = r @ (-2*Wo)^T + bias2 -> d_out

typedef __attribute__((ext_vector_type(8))) short bf16x8;
typedef __attribute__((ext_vector_type(4))) float f32x4;
typedef __attribute__((ext_vector_type(8))) unsigned short u16x8;

#define C2F 2.88539008177792681472f  // 2*log2(e)
#define LOG2E 1.44269504088896340736f

static __device__ __forceinline__ unsigned short f2b(float f) {
  unsigned u = __builtin_bit_cast(unsigned, f);
  unsigned r = 0x7FFFu + ((u >> 16) & 1u);  // round-to-nearest-even
  return (unsigned short)((u + r) >> 16);
}

// global -> LDS async copy, 16B per lane; LDS dest = wave-uniform base + lane*16.
static __device__ __forceinline__ void gload_lds16(const void* g, void* l) {
  __builtin_amdgcn_global_load_lds(
      (const __attribute__((address_space(1))) void*)(uintptr_t)g,
      (__attribute__((address_space(3))) void*)(unsigned)(uintptr_t)l,
      16, 0, 0);
}

// ---------------- f32 -> bf16 convert (with scale), 8 elems/thread ----------------
__global__ __launch_bounds__(256) void cvt_f32_bf16(const float* __restrict__ in,
                                                    unsigned short* __restrict__ out,
                                                    float scale, int n8) {
  int i = blockIdx.x * 256 + threadIdx.x;
  if (i >= n8) return;
  const float4* p = (const float4*)in;
  float4 v0 = p[2 * (size_t)i];
  float4 v1 = p[2 * (size_t)i + 1];
  u16x8 o;
  o[0] = f2b(v0.x * scale); o[1] = f2b(v0.y * scale);
  o[2] = f2b(v0.z * scale); o[3] = f2b(v0.w * scale);
  o[4] = f2b(v1.x * scale); o[5] = f2b(v1.y * scale);
  o[6] = f2b(v1.z * scale); o[7] = f2b(v1.w * scale);
  *(u16x8*)(out + 8 * (size_t)i) = o;
}

// ---------------- dkc[n] = C2 * exp(-min(A[n],10)) ----------------
__global__ __launch_bounds__(256) void dkc_kernel(const float* __restrict__ Av,
                                                  float* __restrict__ dkc, int n) {
  int i = blockIdx.x * 256 + threadIdx.x;
  if (i >= n) return;
  float a = fminf(Av[i], 10.0f);
  dkc[i] = C2F * __builtin_amdgcn_exp2f(-a * LOG2E);
}

// ---------------- bias2[o] = bo[o] + sum_n Wo[o][n] ----------------
__global__ __launch_bounds__(256) void bias2_kernel(const float* __restrict__ Wo,
                                                    const float* __restrict__ bo,
                                                    float* __restrict__ bias2) {
  const int o = blockIdx.x * 4 + (threadIdx.x >> 6);
  const int lane = threadIdx.x & 63;
  const float4* row = (const float4*)(Wo + (size_t)o * 1024);
  float s = 0.0f;
#pragma unroll
  for (int k = 0; k < 4; ++k) {
    float4 v = row[lane + k * 64];
    s += v.x + v.y + v.z + v.w;
  }
#pragma unroll
  for (int off = 32; off; off >>= 1) s += __shfl_down(s, off);
  if (lane == 0) bias2[o] = s + bo[o];
}

// ======== 256x256-tile GEMM, C[M][N] = A[M][K] @ B[N][K]^T, epilogue-fused ========
// 8 waves (2m x 4n), BK=32, 4-deep LDS pipeline (4 bufs x (A 16K + B 16K) = 128KB).
// Per wave: 128x64 output = 8x4 mfma_16x16x32 frags.
// LDS layout (T2 both-sides swizzle, rule #21):
//   byte(row,chunk) = (row>>1)*128 + ((((row&1)<<2)+chunk) ^ ((row>>1)&7))*16
//   (chunk = 16B = 8 bf16 of k). gload_lds dest stays LINEAR; the per-lane GLOBAL
//   source is inverse-permuted; ds_read uses the swizzled byte addr -> conflict-free.
// Schedule per K-tile t: STAGE(t+3) [4 gload_lds] ; s_waitcnt vmcnt(12) ; s_barrier ;
//   ds_read frags + 2x16 MFMA (setprio) ; s_barrier.  Tail peels vmcnt 8/4/0.
// MODE 0: C = acc*C2 + bv[col]   MODE 1: C = acc + bv[col]
template <int MODE>
__global__ __launch_bounds__(512, 1) void gemm256(const unsigned short* __restrict__ A,
                                                  const unsigned short* __restrict__ B,
                                                  float* __restrict__ C,
                                                  const float* __restrict__ bv,
                                                  int M, int N, int K) {
  constexpr int BK = 32;
  __shared__ char lds[4][2][16384];  // [buf][op][16KB] = 128 KiB
  const int tid = threadIdx.x;
  const int wave = tid >> 6, lane = tid & 63;
  const int wr = wave >> 2, wc = wave & 3;

  // T1: XCD-chunked block mapping (grid multiple of 8; bijective).
  const int nbn = N >> 8;
  const int per = gridDim.x >> 3;
  const int tilei = (blockIdx.x & 7) * per + (blockIdx.x >> 3);
  const int m0 = (tilei / nbn) << 8;
  const int n0 = (tilei % nbn) << 8;

  // Staging: per issue i, linear LDS offset o = i*8192 + wave*1024 + lane*16.
  // Invert swizzle to get the (row, chunk) whose data belongs at o.
  int soff[2];
#pragma unroll
  for (int i = 0; i < 2; ++i) {
    int o = i * 8192 + wave * 1024 + lane * 16;
    int rp = o >> 7;
    int p = ((o >> 4) & 7) ^ (rp & 7);
    int row = rp * 2 + (p >> 2);
    int chunk = p & 3;
    soff[i] = row * K + chunk * 8;  // element offset (same formula for A and B)
  }
  const unsigned short* Abase = A + (size_t)m0 * K;
  const unsigned short* Bbase = B + (size_t)n0 * K;

#define STAGE(T_)                                                                \
  {                                                                              \
    const int _buf = (T_) & 3;                                                   \
    const int _k0 = (T_) * BK;                                                   \
    _Pragma("unroll") for (int i = 0; i < 2; ++i) {                              \
      gload_lds16(Abase + _k0 + soff[i], &lds[_buf][0][i * 8192 + wave * 1024]); \
      gload_lds16(Bbase + _k0 + soff[i], &lds[_buf][1][i * 8192 + wave * 1024]); \
    }                                                                            \
  }

  // Swizzled read base addresses (per lane; frag offsets are +mf*1024 / +nf*1024
  // because (row>>1)&7 is invariant under row += 16).
  const int l15 = lane & 15, ck = lane >> 4;
  const int ra = wr * 128 + l15;
  const int rb = wc * 64 + l15;
  const int baseA = (ra >> 1) * 128 + ((((ra & 1) << 2) + ck) ^ ((ra >> 1) & 7)) * 16;
  const int baseB = (rb >> 1) * 128 + ((((rb & 1) << 2) + ck) ^ ((rb >> 1) & 7)) * 16;

  f32x4 acc[8][4] = {};

  STAGE(0); STAGE(1); STAGE(2);  // 12 outstanding

  const int T = K / BK;  // requires T >= 4

#define ITER(T_, WAITN, DOSTAGE)                                                  \
  {                                                                               \
    if (DOSTAGE) STAGE((T_) + 3);                                                 \
    asm volatile("s_waitcnt vmcnt(" #WAITN ")" ::: "memory");                     \
    __builtin_amdgcn_s_barrier();                                                 \
    const char* pa = &lds[(T_) & 3][0][baseA];                                    \
    const char* pb = &lds[(T_) & 3][1][baseB];                                    \
    bf16x8 bfr[4], af[4];                                                         \
    _Pragma("unroll") for (int nf = 0; nf < 4; ++nf)                              \
        bfr[nf] = *(const bf16x8*)(pb + nf * 1024);                               \
    _Pragma("unroll") for (int mf = 0; mf < 4; ++mf)                              \
        af[mf] = *(const bf16x8*)(pa + mf * 1024);                                \
    __builtin_amdgcn_s_setprio(1);                                                \
    _Pragma("unroll") for (int mf = 0; mf < 4; ++mf)                              \
      _Pragma("unroll") for (int nf = 0; nf < 4; ++nf)                            \
        acc[mf][nf] = __builtin_amdgcn_mfma_f32_16x16x32_bf16(af[mf], bfr[nf],    \
                                                              acc[mf][nf], 0, 0, 0); \
    __builtin_amdgcn_s_setprio(0);                                                \
    _Pragma("unroll") for (int mf = 0; mf < 4; ++mf)                              \
        af[mf] = *(const bf16x8*)(pa + (mf + 4) * 1024);                          \
    __builtin_amdgcn_s_setprio(1);                                                \
    _Pragma("unroll") for (int mf = 0; mf < 4; ++mf)                              \
      _Pragma("unroll") for (int nf = 0; nf < 4; ++nf)                            \
        acc[mf + 4][nf] = __builtin_amdgcn_mfma_f32_16x16x32_bf16(                \
            af[mf], bfr[nf], acc[mf + 4][nf], 0, 0, 0);                           \
    __builtin_amdgcn_s_setprio(0);                                                \
    __builtin_amdgcn_s_barrier();                                                 \
  }

  for (int t = 0; t < T - 3; ++t) ITER(t, 12, 1);
  ITER(T - 3, 8, 0);
  ITER(T - 2, 4, 0);
  ITER(T - 1, 0, 0);
#undef ITER
#undef STAGE

  // Epilogue. C/D layout (m89-verified): col = lane&15, row = (lane>>4)*4 + reg
  const int cr = (lane >> 4) * 4;
  const int cc = lane & 15;
#pragma unroll
  for (int nf = 0; nf < 4; ++nf) {
    const int gc = n0 + wc * 64 + nf * 16 + cc;
    const float b = bv[gc];
#pragma unroll
    for (int mf = 0; mf < 8; ++mf) {
      const size_t base = (size_t)(m0 + wr * 128 + mf * 16 + cr) * N + gc;
#pragma unroll
      for (int r = 0; r < 4; ++r) {
        float v = MODE == 0 ? fmaf(acc[mf][nf][r], C2F, b) : (acc[mf][nf][r] + b);
        C[base + (size_t)r * N] = v;
      }
    }
  }
}

// ---------------- sequential scan over t, r-space ----------------
__global__ __launch_bounds__(64) void scan_kernel(const float* __restrict__ Bx,
                                                  const float* __restrict__ Av,
                                                  unsigned short* __restrict__ h) {
  constexpr int S = 2048, D = 1024, U = 8;
  const unsigned gid = blockIdx.x * 64 + threadIdx.x;
  const unsigned b = gid >> 10;
  const unsigned n = gid & (D - 1);

  const float a = fminf(Av[n], 10.0f);
  const float dec = __builtin_amdgcn_exp2f(-a * LOG2E);
  const float m2dk = -2.0f * C2F * dec;

  const unsigned base = b * (unsigned)(S * D) + n;

  float b0[U], b1[U], b2[U], b3[U];
#pragma unroll
  for (int j = 0; j < U; ++j) b0[j] = Bx[base + (0 * U + j) * D];
#pragma unroll
  for (int j = 0; j < U; ++j) b1[j] = Bx[base + (1 * U + j) * D];
#pragma unroll
  for (int j = 0; j < U; ++j) b2[j] = Bx[base + (2 * U + j) * D];
#pragma unroll
  for (int j = 0; j < U; ++j) b3[j] = Bx[base + (3 * U + j) * D];

  float r = 0.5f;  // s = 1 - 2r = 0

#define STEP(BUF, T)                                              \
  {                                                               \
    float w = fmaf(m2dk, r, BUF);                                 \
    float e = __builtin_amdgcn_exp2f(w);                          \
    r = __builtin_amdgcn_rcpf(e + 1.0f);                          \
    unsigned u = __builtin_bit_cast(unsigned, r);                 \
    u = u + 0x7FFFu + ((u >> 16) & 1u);                           \
    h[base + (unsigned)(T) * D] = (unsigned short)(u >> 16);      \
  }

  for (int t0 = 0; t0 < S; t0 += 4 * U) {
#pragma unroll
    for (int j = 0; j < U; ++j) STEP(b0[j], t0 + j);
    if (t0 + 4 * U < S) {
#pragma unroll
      for (int j = 0; j < U; ++j) b0[j] = Bx[base + (t0 + 4 * U + j) * D];
    }
#pragma unroll
    for (int j = 0; j < U; ++j) STEP(b1[j], t0 + U + j);
    if (t0 + 5 * U < S) {
#pragma unroll
      for (int j = 0; j < U; ++j) b1[j] = Bx[base + (t0 + 5 * U + j) * D];
    }
#pragma unroll
    for (int j = 0; j < U; ++j) STEP(b2[j], t0 + 2 * U + j);
    if (t0 + 6 * U < S) {
#pragma unroll
      for (int j = 0; j < U; ++j) b2[j] = Bx[base + (t0 + 6 * U + j) * D];
    }
#pragma unroll
    for (int j = 0; j < U; ++j) STEP(b3[j], t0 + 3 * U + j);
    if (t0 + 7 * U < S) {
#pragma unroll
      for (int j = 0; j < U; ++j) b3[j] = Bx[base + (t0 + 7 * U + j) * D];
    }
  }
#undef STEP
}

extern "C" void kernel_launch(void* const* d_in, const int* in_sizes, int n_in,
                              void* d_out, int out_size, void* d_ws, size_t ws_size,
                              hipStream_t stream) {
  const float* x  = (const float*)d_in[0];
  const float* Av = (const float*)d_in[1];
  const float* Bw = (const float*)d_in[2];
  const float* Wo = (const float*)d_in[3];
  const float* bo = (const float*)d_in[4];
  float* out = (float*)d_out;

  const int Bsz = 8, S = 2048, Din = 1024, Dst = 1024, Dout = 1024;
  const int M = Bsz * S;  // 16384

  char* ws = (char*)d_ws;
  unsigned short* x_bf  = (unsigned short*)ws;
  unsigned short* r_bf  = (unsigned short*)(ws + (size_t)M * Din * 2);
  unsigned short* Bw_bf = (unsigned short*)(ws + (size_t)M * Din * 4);
  unsigned short* Wo_bf = (unsigned short*)(ws + (size_t)M * Din * 4 + (size_t)Dst * Din * 2);
  float* dkc   = (float*)(ws + (size_t)M * Din * 4 + (size_t)Dst * Din * 4);
  float* bias2 = dkc + Dst;

  float* Bx = out;  // d_out doubles as pre-scan scratch (c'' values)

  { int n8 = M * Din / 8;
    cvt_f32_bf16<<<(n8 + 255) / 256, 256, 0, stream>>>(x, x_bf, 1.0f, n8); }
  { int n8 = Dst * Din / 8;
    cvt_f32_bf16<<<(n8 + 255) / 256, 256, 0, stream>>>(Bw, Bw_bf, 1.0f, n8); }
  { int n8 = Dout * Dst / 8;
    cvt_f32_bf16<<<(n8 + 255) / 256, 256, 0, stream>>>(Wo, Wo_bf, -2.0f, n8); }
  dkc_kernel<<<4, 256, 0, stream>>>(Av, dkc, Dst);
  bias2_kernel<<<Dout / 4, 256, 0, stream>>>(Wo, bo, bias2);

  gemm256<0><<<dim3((M / 256) * (Dst / 256)), 512, 0, stream>>>(x_bf, Bw_bf, Bx, dkc, M, Dst, Din);
  scan_kernel<<<dim3((Bsz * Dst) / 64), 64, 0, stream>>>(Bx, Av, r_bf);
  gemm256<1><<<dim3((M / 256) * (Dout / 256)), 512, 0, stream>>>(r_bf, Wo_bf, out, bias2, M, Dout, Dst);
}

// Round 4
// 148.500 us; speedup vs baseline: 1.5204x; 1.1934x over previous
//
#include <hip/hip_runtime.h>
#include <stdint.h>

// DiagonalSSM: out = (scan_t tanh(exp(-A)*state + (x@Bw^T)_t)) @ Wo^T + bo
// B=8, S=2048, Din=Dstate=Dout=1024, fp32 in/out.
//
// Pipeline:
//   cvt x,Bw -> bf16; cvt Wo -> bf16 * (-2); dkc[n] = C2*exp(-min(A,10));
//   bias2[o] = bo[o] + rowsum(Wo)[o]
//   GEMM1 (256^2 tile, 4-deep vmcnt-counted pipe): c'' = C2*(x@Bw^T)+dkc -> d_out
//   scan (r-space, time-chunked w/ 384-step warmup, 2 chains/thread):
//        r_t = rcp(exp2(fma(-2*C2*dec, r_{t-1}, c''_t))+1) -> bf16 ws
//   GEMM2: out = r @ (-2*Wo)^T + bias2 -> d_out

typedef __attribute__((ext_vector_type(8))) short bf16x8;
typedef __attribute__((ext_vector_type(4))) float f32x4;
typedef __attribute__((ext_vector_type(8))) unsigned short u16x8;

#define C2F 2.88539008177792681472f  // 2*log2(e)
#define LOG2E 1.44269504088896340736f

static __device__ __forceinline__ unsigned short f2b(float f) {
  unsigned u = __builtin_bit_cast(unsigned, f);
  unsigned r = 0x7FFFu + ((u >> 16) & 1u);  // round-to-nearest-even
  return (unsigned short)((u + r) >> 16);
}

// global -> LDS async copy, 16B per lane; LDS dest = wave-uniform base + lane*16.
static __device__ __forceinline__ void gload_lds16(const void* g, void* l) {
  __builtin_amdgcn_global_load_lds(
      (const __attribute__((address_space(1))) void*)(uintptr_t)g,
      (__attribute__((address_space(3))) void*)(unsigned)(uintptr_t)l,
      16, 0, 0);
}

// ---------------- f32 -> bf16 convert (with scale), 8 elems/thread ----------------
__global__ __launch_bounds__(256) void cvt_f32_bf16(const float* __restrict__ in,
                                                    unsigned short* __restrict__ out,
                                                    float scale, int n8) {
  int i = blockIdx.x * 256 + threadIdx.x;
  if (i >= n8) return;
  const float4* p = (const float4*)in;
  float4 v0 = p[2 * (size_t)i];
  float4 v1 = p[2 * (size_t)i + 1];
  u16x8 o;
  o[0] = f2b(v0.x * scale); o[1] = f2b(v0.y * scale);
  o[2] = f2b(v0.z * scale); o[3] = f2b(v0.w * scale);
  o[4] = f2b(v1.x * scale); o[5] = f2b(v1.y * scale);
  o[6] = f2b(v1.z * scale); o[7] = f2b(v1.w * scale);
  *(u16x8*)(out + 8 * (size_t)i) = o;
}

// ---------------- dkc[n] = C2 * exp(-min(A[n],10)) ----------------
__global__ __launch_bounds__(256) void dkc_kernel(const float* __restrict__ Av,
                                                  float* __restrict__ dkc, int n) {
  int i = blockIdx.x * 256 + threadIdx.x;
  if (i >= n) return;
  float a = fminf(Av[i], 10.0f);
  dkc[i] = C2F * __builtin_amdgcn_exp2f(-a * LOG2E);
}

// ---------------- bias2[o] = bo[o] + sum_n Wo[o][n] ----------------
__global__ __launch_bounds__(256) void bias2_kernel(const float* __restrict__ Wo,
                                                    const float* __restrict__ bo,
                                                    float* __restrict__ bias2) {
  const int o = blockIdx.x * 4 + (threadIdx.x >> 6);
  const int lane = threadIdx.x & 63;
  const float4* row = (const float4*)(Wo + (size_t)o * 1024);
  float s = 0.0f;
#pragma unroll
  for (int k = 0; k < 4; ++k) {
    float4 v = row[lane + k * 64];
    s += v.x + v.y + v.z + v.w;
  }
#pragma unroll
  for (int off = 32; off; off >>= 1) s += __shfl_down(s, off);
  if (lane == 0) bias2[o] = s + bo[o];
}

// ======== 256x256-tile GEMM, C[M][N] = A[M][K] @ B[N][K]^T, epilogue-fused ========
// (unchanged from R3; see comments there)
template <int MODE>
__global__ __launch_bounds__(512, 1) void gemm256(const unsigned short* __restrict__ A,
                                                  const unsigned short* __restrict__ B,
                                                  float* __restrict__ C,
                                                  const float* __restrict__ bv,
                                                  int M, int N, int K) {
  constexpr int BK = 32;
  __shared__ char lds[4][2][16384];  // [buf][op][16KB] = 128 KiB
  const int tid = threadIdx.x;
  const int wave = tid >> 6, lane = tid & 63;
  const int wr = wave >> 2, wc = wave & 3;

  const int nbn = N >> 8;
  const int per = gridDim.x >> 3;
  const int tilei = (blockIdx.x & 7) * per + (blockIdx.x >> 3);
  const int m0 = (tilei / nbn) << 8;
  const int n0 = (tilei % nbn) << 8;

  int soff[2];
#pragma unroll
  for (int i = 0; i < 2; ++i) {
    int o = i * 8192 + wave * 1024 + lane * 16;
    int rp = o >> 7;
    int p = ((o >> 4) & 7) ^ (rp & 7);
    int row = rp * 2 + (p >> 2);
    int chunk = p & 3;
    soff[i] = row * K + chunk * 8;
  }
  const unsigned short* Abase = A + (size_t)m0 * K;
  const unsigned short* Bbase = B + (size_t)n0 * K;

#define STAGE(T_)                                                                \
  {                                                                              \
    const int _buf = (T_) & 3;                                                   \
    const int _k0 = (T_) * BK;                                                   \
    _Pragma("unroll") for (int i = 0; i < 2; ++i) {                              \
      gload_lds16(Abase + _k0 + soff[i], &lds[_buf][0][i * 8192 + wave * 1024]); \
      gload_lds16(Bbase + _k0 + soff[i], &lds[_buf][1][i * 8192 + wave * 1024]); \
    }                                                                            \
  }

  const int l15 = lane & 15, ck = lane >> 4;
  const int ra = wr * 128 + l15;
  const int rb = wc * 64 + l15;
  const int baseA = (ra >> 1) * 128 + ((((ra & 1) << 2) + ck) ^ ((ra >> 1) & 7)) * 16;
  const int baseB = (rb >> 1) * 128 + ((((rb & 1) << 2) + ck) ^ ((rb >> 1) & 7)) * 16;

  f32x4 acc[8][4] = {};

  STAGE(0); STAGE(1); STAGE(2);  // 12 outstanding

  const int T = K / BK;  // requires T >= 4

#define ITER(T_, WAITN, DOSTAGE)                                                  \
  {                                                                               \
    if (DOSTAGE) STAGE((T_) + 3);                                                 \
    asm volatile("s_waitcnt vmcnt(" #WAITN ")" ::: "memory");                     \
    __builtin_amdgcn_s_barrier();                                                 \
    const char* pa = &lds[(T_) & 3][0][baseA];                                    \
    const char* pb = &lds[(T_) & 3][1][baseB];                                    \
    bf16x8 bfr[4], af[4];                                                         \
    _Pragma("unroll") for (int nf = 0; nf < 4; ++nf)                              \
        bfr[nf] = *(const bf16x8*)(pb + nf * 1024);                               \
    _Pragma("unroll") for (int mf = 0; mf < 4; ++mf)                              \
        af[mf] = *(const bf16x8*)(pa + mf * 1024);                                \
    __builtin_amdgcn_s_setprio(1);                                                \
    _Pragma("unroll") for (int mf = 0; mf < 4; ++mf)                              \
      _Pragma("unroll") for (int nf = 0; nf < 4; ++nf)                            \
        acc[mf][nf] = __builtin_amdgcn_mfma_f32_16x16x32_bf16(af[mf], bfr[nf],    \
                                                              acc[mf][nf], 0, 0, 0); \
    __builtin_amdgcn_s_setprio(0);                                                \
    _Pragma("unroll") for (int mf = 0; mf < 4; ++mf)                              \
        af[mf] = *(const bf16x8*)(pa + (mf + 4) * 1024);                          \
    __builtin_amdgcn_s_setprio(1);                                                \
    _Pragma("unroll") for (int mf = 0; mf < 4; ++mf)                              \
      _Pragma("unroll") for (int nf = 0; nf < 4; ++nf)                            \
        acc[mf + 4][nf] = __builtin_amdgcn_mfma_f32_16x16x32_bf16(                \
            af[mf], bfr[nf], acc[mf + 4][nf], 0, 0, 0);                           \
    __builtin_amdgcn_s_setprio(0);                                                \
    __builtin_amdgcn_s_barrier();                                                 \
  }

  for (int t = 0; t < T - 3; ++t) ITER(t, 12, 1);
  ITER(T - 3, 8, 0);
  ITER(T - 2, 4, 0);
  ITER(T - 1, 0, 0);
#undef ITER
#undef STAGE

  const int cr = (lane >> 4) * 4;
  const int cc = lane & 15;
#pragma unroll
  for (int nf = 0; nf < 4; ++nf) {
    const int gc = n0 + wc * 64 + nf * 16 + cc;
    const float b = bv[gc];
#pragma unroll
    for (int mf = 0; mf < 8; ++mf) {
      const size_t base = (size_t)(m0 + wr * 128 + mf * 16 + cr) * N + gc;
#pragma unroll
      for (int r = 0; r < 4; ++r) {
        float v = MODE == 0 ? fmaf(acc[mf][nf][r], C2F, b) : (acc[mf][nf][r] + b);
        C[base + (size_t)r * N] = v;
      }
    }
  }
}

// ---------------- time-chunked scan, r-space, 2 adjacent channels/thread ----------------
// S split into 8 chunks of 256. Chunk c starts from state=0 at t = max(0, c*256-384):
// warmup steps (no store) contract the wrong-init error by prod(dec*sech^2) —
// worst-case (A~0, s~0) E[ln g] ~ -E[w^2] = -0.034/step => e^{-13} over 384 steps.
// Thread owns channels (2p, 2p+1): float2 loads, packed dword bf16 stores (cvt_pk).
// Grid: 8 b x 8 chunks x 2 halves = 128 blocks x 256 thr = 512 waves.
__global__ __launch_bounds__(256) void scan_kernel(const float* __restrict__ Bx,
                                                   const float* __restrict__ Av,
                                                   unsigned short* __restrict__ h) {
  constexpr int S = 2048, D = 1024, CHUNK = 256, W = 384;
  const int bid = blockIdx.x;
  const int half = bid & 1;
  const int chunk = (bid >> 1) & 7;
  const int b = bid >> 4;
  const int p = half * 256 + threadIdx.x;  // 0..511
  const unsigned n0 = 2u * p;

  const float2 av = *(const float2*)(Av + n0);
  const float m2dk0 = -2.0f * C2F * __builtin_amdgcn_exp2f(-fminf(av.x, 10.0f) * LOG2E);
  const float m2dk1 = -2.0f * C2F * __builtin_amdgcn_exp2f(-fminf(av.y, 10.0f) * LOG2E);

  const unsigned base = (unsigned)b * (S * D) + n0;
  const int t_store0 = chunk * CHUNK;
  const int t_start = (chunk * CHUNK - W) < 0 ? 0 : (chunk * CHUNK - W);
  const int t_end = t_store0 + CHUNK;

  float2 A[8], Bf[8];
#pragma unroll
  for (int j = 0; j < 8; ++j) A[j] = *(const float2*)(Bx + base + (unsigned)(t_start + j) * D);
#pragma unroll
  for (int j = 0; j < 8; ++j) Bf[j] = *(const float2*)(Bx + base + (unsigned)(t_start + 8 + j) * D);

  float r0 = 0.5f, r1 = 0.5f;  // s = 1-2r = 0

#define STEP2(CV)                                         \
  {                                                       \
    float w0 = fmaf(m2dk0, r0, (CV).x);                   \
    float w1 = fmaf(m2dk1, r1, (CV).y);                   \
    float e0 = __builtin_amdgcn_exp2f(w0);                \
    float e1 = __builtin_amdgcn_exp2f(w1);                \
    r0 = __builtin_amdgcn_rcpf(e0 + 1.0f);                \
    r1 = __builtin_amdgcn_rcpf(e1 + 1.0f);                \
  }

#define STORE2(T_)                                                        \
  {                                                                       \
    unsigned pk;                                                          \
    asm("v_cvt_pk_bf16_f32 %0, %1, %2" : "=v"(pk) : "v"(r0), "v"(r1));    \
    *(unsigned*)(h + base + (unsigned)(T_) * D) = pk;                     \
  }

  // warmup (no stores); lengths are multiples of 16
  for (int t0 = t_start; t0 < t_store0; t0 += 16) {
#pragma unroll
    for (int j = 0; j < 8; ++j) STEP2(A[j]);
#pragma unroll
    for (int j = 0; j < 8; ++j) A[j] = *(const float2*)(Bx + base + (unsigned)(t0 + 16 + j) * D);
#pragma unroll
    for (int j = 0; j < 8; ++j) STEP2(Bf[j]);
#pragma unroll
    for (int j = 0; j < 8; ++j) Bf[j] = *(const float2*)(Bx + base + (unsigned)(t0 + 24 + j) * D);
  }
  // stored region
  for (int t0 = t_store0; t0 < t_end; t0 += 16) {
#pragma unroll
    for (int j = 0; j < 8; ++j) { STEP2(A[j]); STORE2(t0 + j); }
    if (t0 + 16 < t_end) {
#pragma unroll
      for (int j = 0; j < 8; ++j) A[j] = *(const float2*)(Bx + base + (unsigned)(t0 + 16 + j) * D);
    }
#pragma unroll
    for (int j = 0; j < 8; ++j) { STEP2(Bf[j]); STORE2(t0 + 8 + j); }
    if (t0 + 24 < t_end) {
#pragma unroll
      for (int j = 0; j < 8; ++j) Bf[j] = *(const float2*)(Bx + base + (unsigned)(t0 + 24 + j) * D);
    }
  }
#undef STEP2
#undef STORE2
}

extern "C" void kernel_launch(void* const* d_in, const int* in_sizes, int n_in,
                              void* d_out, int out_size, void* d_ws, size_t ws_size,
                              hipStream_t stream) {
  const float* x  = (const float*)d_in[0];
  const float* Av = (const float*)d_in[1];
  const float* Bw = (const float*)d_in[2];
  const float* Wo = (const float*)d_in[3];
  const float* bo = (const float*)d_in[4];
  float* out = (float*)d_out;

  const int Bsz = 8, S = 2048, Din = 1024, Dst = 1024, Dout = 1024;
  const int M = Bsz * S;  // 16384

  char* ws = (char*)d_ws;
  unsigned short* x_bf  = (unsigned short*)ws;
  unsigned short* r_bf  = (unsigned short*)(ws + (size_t)M * Din * 2);
  unsigned short* Bw_bf = (unsigned short*)(ws + (size_t)M * Din * 4);
  unsigned short* Wo_bf = (unsigned short*)(ws + (size_t)M * Din * 4 + (size_t)Dst * Din * 2);
  float* dkc   = (float*)(ws + (size_t)M * Din * 4 + (size_t)Dst * Din * 4);
  float* bias2 = dkc + Dst;

  float* Bx = out;  // d_out doubles as pre-scan scratch (c'' values)

  { int n8 = M * Din / 8;
    cvt_f32_bf16<<<(n8 + 255) / 256, 256, 0, stream>>>(x, x_bf, 1.0f, n8); }
  { int n8 = Dst * Din / 8;
    cvt_f32_bf16<<<(n8 + 255) / 256, 256, 0, stream>>>(Bw, Bw_bf, 1.0f, n8); }
  { int n8 = Dout * Dst / 8;
    cvt_f32_bf16<<<(n8 + 255) / 256, 256, 0, stream>>>(Wo, Wo_bf, -2.0f, n8); }
  dkc_kernel<<<4, 256, 0, stream>>>(Av, dkc, Dst);
  bias2_kernel<<<Dout / 4, 256, 0, stream>>>(Wo, bo, bias2);

  gemm256<0><<<dim3((M / 256) * (Dst / 256)), 512, 0, stream>>>(x_bf, Bw_bf, Bx, dkc, M, Dst, Din);
  scan_kernel<<<dim3(128), 256, 0, stream>>>(Bx, Av, r_bf);
  gemm256<1><<<dim3((M / 256) * (Dout / 256)), 512, 0, stream>>>(r_bf, Wo_bf, out, bias2, M, Dout, Dst);
}